// Round 1
// baseline (142.163 us; speedup 1.0000x reference)
//
#include <hip/hip_runtime.h>
#include <math.h>

// DimIxLoss reduces algebraically to a constant:
//   xy = matmul_topk_loss(x,y).mean()            -> scalar
//   xy = exp(-xy + min(xy) - 0.1)                -> min(scalar)==scalar
//      = exp(0.0 - 0.1) = exp(-0.1)              (exact FP cancellation)
// total = 3 * exp(-0.1), independent of x,y,z.
// So the optimal kernel is a single-element constant store. We still
// compute expf(-0.1f) on-device (same work every call, graph-capture safe).

__global__ void DimIxLoss_2379411882005_kernel(float* __restrict__ out) {
    if (threadIdx.x == 0 && blockIdx.x == 0) {
        float e = expf(-0.1f);
        out[0] = e + e + e;   // 3 * exp(-0.1) = 2.7145122...
    }
}

extern "C" void kernel_launch(void* const* d_in, const int* in_sizes, int n_in,
                              void* d_out, int out_size, void* d_ws, size_t ws_size,
                              hipStream_t stream) {
    (void)d_in; (void)in_sizes; (void)n_in; (void)out_size;
    (void)d_ws; (void)ws_size;
    float* out = (float*)d_out;
    DimIxLoss_2379411882005_kernel<<<1, 64, 0, stream>>>(out);
}